// Round 8
// baseline (46.885 us; speedup 1.0000x reference)
//
#include <hip/hip_runtime.h>
#include <stdint.h>

// 4-point Hermite resampler — barrier-free wave-private LDS pipeline, v5.
// vs v4: (1) tail folded into the main launch as grid.x slice `full`
// (concurrent with main blocks instead of a serialized 2nd kernel);
// (2) 128-thread / 2-wave blocks: TILE=512, 2x the blocks -> finer load
// balance; 16 blocks x 2 waves = 32 waves/CU, LDS 16 x 9.2 KB = 147 KB.
// Pipeline unchanged: depth-3 channel prefetch via global_load_lds into 4
// wave-private buffers, store-aware counted vmcnt (prologue 6/7/8, steady 9:
// each wait retires one store + the 2 loads of the buffer about to be read).
// x / y0 computed on device from fp64 scaling (bitwise == numpy).

#define NW   2
#define OPW  256
#define TILE (NW * OPW)    // 512 outputs per block
#define WFL  288           // staged floats per window (need <=283)
#define CPB  8             // channels per block (grid.y = 4)
#define NCH  32

typedef float vf4 __attribute__((ext_vector_type(4)));

typedef const __attribute__((address_space(1))) uint32_t* gas_t;
typedef __attribute__((address_space(3))) uint32_t* las_t;

__device__ __forceinline__ void stage_win(const float* g, float* l, int lane) {
    // lane i: 16B from g+16i -> LDS l+16i (wave-uniform LDS base, linear)
    __builtin_amdgcn_global_load_lds((gas_t)g, (las_t)l, 16, 0, 0);
    if (lane < 8)   // floats [256, 288)
        __builtin_amdgcn_global_load_lds((gas_t)(g + 256), (las_t)(l + 256), 16, 0, 0);
}

template<bool INTERIOR>
__device__ __forceinline__ void run(
    const float* __restrict__ gb, float* __restrict__ op, size_t chstride,
    int out_bs, float* b0, float* b1, float* b2, float* b3, int lane,
    const int* rr, const int* am1, const int* a1, const int* a2,
    const float* xw)
{
    stage_win(gb + 0 * chstride, b0, lane);
    stage_win(gb + 1 * chstride, b1, lane);
    stage_win(gb + 2 * chstride, b2, lane);

#define HBODY(S, CUR, NXT, CNT)                                               \
  {                                                                           \
    const int sn = ((S) + 3 < CPB) ? (S) + 3 : CPB - 1;  /* dead restage */   \
    stage_win(gb + (size_t)sn * chstride, NXT, lane);                         \
    asm volatile("s_waitcnt vmcnt(" #CNT ")" ::: "memory");                   \
    __builtin_amdgcn_sched_barrier(0);                                        \
    vf4 o;                                                                    \
    _Pragma("unroll")                                                         \
    for (int k = 0; k < 4; ++k) {                                             \
      float ym1, y0f, y1f, y2f;                                               \
      if (INTERIOR) {                                                         \
        const float* p = (CUR) + rr[k];                                       \
        ym1 = p[-1]; y0f = p[0]; y1f = p[1]; y2f = p[2];                      \
      } else {                                                                \
        ym1 = (CUR)[am1[k]]; y0f = (CUR)[rr[k]];                              \
        y1f = (CUR)[a1[k]];  y2f = (CUR)[a2[k]];                              \
      }                                                                       \
      const float c1 = 0.5f * (y1f - ym1);                                    \
      const float c2 = ym1 - 2.5f * y0f + 2.0f * y1f - 0.5f * y2f;            \
      const float c3 = 0.5f * (y2f - ym1) + 1.5f * (y0f - y1f);               \
      const float xx = xw[k];                                                 \
      o[k] = ((c3 * xx + c2) * xx + c1) * xx + y0f;                           \
    }                                                                         \
    __builtin_nontemporal_store(o, (vf4*)(op + (size_t)(S) * (size_t)out_bs)); \
  }

    HBODY(0, b0, b3, 6)
    HBODY(1, b1, b0, 7)
    HBODY(2, b2, b1, 8)
    HBODY(3, b3, b2, 9)
    for (int ss = 4; ss < CPB; ss += 4) {
        HBODY(ss + 0, b0, b3, 9)
        HBODY(ss + 1, b1, b0, 9)
        HBODY(ss + 2, b2, b1, 9)
        HBODY(ss + 3, b3, b2, 9)
    }
#undef HBODY
}

__global__ __launch_bounds__(128) void hermite_main_kernel(
    const float* __restrict__ y,       // [32, in_bs]
    float* __restrict__ out,           // [32, out_bs]
    int out_bs, int in_bs, double scaling, int full)
{
    __shared__ float sbuf[NW][4][WFL];   // 9.2 KB -> 16 blocks/CU
    const int t    = threadIdx.x;
    const int w    = t >> 6;
    const int lane = t & 63;
    const int ch0  = blockIdx.y * CPB;

    if ((int)blockIdx.x == full) {
        // ---- tail slice: simple gather path, runs concurrent with main ----
        const int j_tail = full * TILE;
        const int n_tail = out_bs - j_tail;
        for (int idx = t; idx < n_tail * CPB; idx += 128) {
            const int jr = idx % n_tail;
            const int ch = ch0 + idx / n_tail;
            const int j  = j_tail + jr;
            const double xf = (double)j * scaling;
            const double fl = __builtin_floor(xf);
            const int    y0 = (int)fl;
            double xd = fmin(fmax(xf - fl, 0.0), 1.0);
            if (j == out_bs - 1) xd = __builtin_rint(xd);  // np: x[-1]=round
            const float xx = (float)xd;
            const float* yc = y + (size_t)ch * (size_t)in_bs;
            const float ym1 = yc[max(y0 - 1, 0)];
            const float y0f = yc[y0];
            const float y1f = yc[min(y0 + 1, in_bs - 1)];
            const float y2f = yc[min(y0 + 2, in_bs - 1)];
            const float c1 = 0.5f * (y1f - ym1);
            const float c2 = ym1 - 2.5f * y0f + 2.0f * y1f - 0.5f * y2f;
            const float c3 = 0.5f * (y2f - ym1) + 1.5f * (y0f - y1f);
            out[(size_t)ch * (size_t)out_bs + j] =
                ((c3 * xx + c2) * xx + c1) * xx + y0f;
        }
        return;
    }

    const int jw = blockIdx.x * TILE + w * OPW;   // full tiles only
    const int j  = jw + 4 * lane;                 // thread's 4 outputs

    // wave-uniform window base from computed y0(jw), 16B-aligned
    const int y0w = (int)__builtin_floor((double)jw * scaling);
    int src = (y0w - 1) & ~3;
    src = max(src, 0);
    src = min(src, in_bs - WFL);

    // per-thread x and tap offsets (bitwise-identical to numpy fp64 path),
    // loop-invariant across channels
    float xw[4]; int rr[4], am1[4], a1[4], a2[4];
    #pragma unroll
    for (int k = 0; k < 4; ++k) {
        const int    jk = j + k;
        const double xf = (double)jk * scaling;
        const double fl = __builtin_floor(xf);
        const int    y0 = (int)fl;
        xw[k]  = (float)fmin(fmax(xf - fl, 0.0), 1.0);
        rr[k]  = y0 - src;
        am1[k] = max(y0 - 1, 0) - src;
        a1[k]  = min(y0 + 1, in_bs - 1) - src;
        a2[k]  = min(y0 + 2, in_bs - 1) - src;
    }

    const float* gb = y + (size_t)ch0 * (size_t)in_bs + src + 4 * lane;
    float*       op = out + (size_t)ch0 * (size_t)out_bs + j;
    float* b0 = &sbuf[w][0][0];
    float* b1 = &sbuf[w][1][0];
    float* b2 = &sbuf[w][2][0];
    float* b3 = &sbuf[w][3][0];

    // only tile 0 / wave 0 can hit the y0-1 clamp; end clamps never bind in
    // full tiles (max y0+2 << in_bs-1)
    const bool interior = (src >= 4) && (src + WFL + 4 <= in_bs);
    if (interior)
        run<true >(gb, op, (size_t)in_bs, out_bs, b0, b1, b2, b3, lane,
                   rr, am1, a1, a2, xw);
    else
        run<false>(gb, op, (size_t)in_bs, out_bs, b0, b1, b2, b3, lane,
                   rr, am1, a1, a2, xw);
}

extern "C" void kernel_launch(void* const* d_in, const int* in_sizes, int n_in,
                              void* d_out, int out_size, void* d_ws, size_t ws_size,
                              hipStream_t stream)
{
    const float* y   = (const float*)d_in[0];
    float*       out = (float*)d_out;

    const int out_bs = in_sizes[1];           // 963380
    const int n_ch   = out_size / out_bs;     // 32
    const int in_bs  = in_sizes[0] / n_ch;    // 1048576

    // identical IEEE fp64 value to numpy's (in_bs-1)/(out_bs-1) + 1e-12
    const double scaling = (double)(in_bs - 1) / (double)(out_bs - 1) + 1e-12;

    const int full = out_bs / TILE;           // 1881 full tiles (tail = 308)

    dim3 grid(full + 1, n_ch / CPB, 1);       // (1882, 4), slice `full` = tail
    hermite_main_kernel<<<grid, 128, 0, stream>>>(
        y, out, out_bs, in_bs, scaling, full);
}

// Round 9
// 46.651 us; speedup vs baseline: 1.0050x; 1.0050x over previous
//
#include <hip/hip_runtime.h>
#include <stdint.h>

// 4-point Hermite resampler — persistent fine-grained wave pipeline, v6.
// 4096 blocks x 128 thr = 8192 waves, ALL co-resident (16 blk/CU: 5.1 KB LDS,
// VGPR<=64 via launch_bounds). Work = ntile*16 units (unit = 128 outputs x 2
// channels); wave g owns units g, g+8192, ... (14-15 each, 2% max skew) ->
// no block-requeue quantization (was ~4.2 us). Per unit: 2 windows (ch0,
// ch0+1) through a ring-4 LDS buffer pipeline, depth-3 window lookahead via
// global_load_lds (640 B/window), store-aware counted vmcnt: 3,4,5, steady 6.
// x/y0 from exact 43-bit fixed point (j*S43>>43); floor-boundary flips are
// harmless (Hermite endpoint-exact: H(1)=y1). Tail + tile-0 clamps handled
// by spare waves / wave-uniform fallback.

#define TILE        128
#define WFL         160      // staged floats per window (need 146)
#define STAGE_LANES 40       // 40 lanes x 16 B = 640 B
#define NCH         32
#define NBLOCKS     4096
#define NWAVES      8192
#define FRACSH      43

typedef float vf2 __attribute__((ext_vector_type(2)));
typedef const __attribute__((address_space(1))) uint32_t* gas_t;
typedef __attribute__((address_space(3))) uint32_t* las_t;

__device__ __forceinline__ float herm(float ym1, float y0f, float y1f,
                                      float y2f, float xx) {
    const float c1 = 0.5f * (y1f - ym1);
    const float c2 = ym1 - 2.5f * y0f + 2.0f * y1f - 0.5f * y2f;
    const float c3 = 0.5f * (y2f - ym1) + 1.5f * (y0f - y1f);
    return ((c3 * xx + c2) * xx + c1) * xx + y0f;
}

__global__ __launch_bounds__(128, 8) void hermite_pers_kernel(
    const float* __restrict__ y,       // [32, in_bs]
    float* __restrict__ out,           // [32, out_bs]
    int out_bs, int in_bs, unsigned long long S43, int ntile, int tailn)
{
    __shared__ float sbuf[2][4][WFL];
    const int w    = threadIdx.x >> 6;
    const int lane = threadIdx.x & 63;
    const int gid  = blockIdx.x * 2 + w;

    const int chpair = gid & 15;
    const int ti0    = gid >> 4;                    // base tile, stride 512
    const int U      = ntile * 16;
    const int nu     = (U - gid + NWAVES - 1) / NWAVES;   // units: 14 or 15

    const float* ybA = y + (size_t)(chpair * 2) * (size_t)in_bs;
    const float* ybB = ybA + in_bs;
    float* outA = out + (size_t)(chpair * 2) * (size_t)out_bs;

    float* b0 = &sbuf[w][0][0];
    float* b1 = &sbuf[w][1][0];
    float* b2 = &sbuf[w][2][0];
    float* b3 = &sbuf[w][3][0];

    auto src_of = [&](int tile) -> int {
        const int jw = tile << 7;
        const uint64_t pw = (uint64_t)(uint32_t)jw * S43;
        const int y0w = (int)(pw >> FRACSH);
        int s = (y0w - 1) & ~3;
        s = s < 0 ? 0 : s;
        const int smax = in_bs - WFL;
        return s > smax ? smax : s;     // provably no-op; safety
    };

    int t_cur = ti0;
    int s0 = src_of(ti0);
    int s1 = src_of(ti0 + 512);
    int s2 = src_of(ti0 + 1024);

    int ra = 0, rb = 0;
    float xa = 0.f, xb = 0.f;
    float* oA = outA;

#define STAGE(GPTR, LBUF) do { if (lane < STAGE_LANES)                        \
    __builtin_amdgcn_global_load_lds((gas_t)(GPTR), (las_t)(LBUF), 16, 0, 0); \
  } while (0)

#define TAPS() do {                                                           \
    const int jw_ = t_cur << 7;                                               \
    const int j0_ = jw_ + 2 * lane;                                           \
    const uint64_t p0_ = (uint64_t)(uint32_t)j0_ * S43;                       \
    const uint64_t p1_ = p0_ + S43;                                           \
    ra = (int)(p0_ >> FRACSH) - s0;                                           \
    rb = (int)(p1_ >> FRACSH) - s0;                                           \
    xa = (float)((uint32_t)(p0_ >> (FRACSH - 24)) & 0xFFFFFFu) * 0x1p-24f;    \
    xb = (float)((uint32_t)(p1_ >> (FRACSH - 24)) & 0xFFFFFFu) * 0x1p-24f;    \
    oA = outA + jw_ + 2 * lane;                                               \
  } while (0)

#define WCOMP(WAITN, LBUF, OPTR) do {                                         \
    asm volatile("s_waitcnt vmcnt(" #WAITN ")" ::: "memory");                 \
    __builtin_amdgcn_sched_barrier(0);                                        \
    const float* pa_ = (LBUF) + ra;                                           \
    const float* pb_ = (LBUF) + rb;                                           \
    vf2 o_;                                                                   \
    o_.x = herm(pa_[-1], pa_[0], pa_[1], pa_[2], xa);                         \
    o_.y = herm(pb_[-1], pb_[0], pb_[1], pb_[2], xb);                         \
    __builtin_nontemporal_store(o_, (vf2*)(OPTR));                            \
  } while (0)

#define ROLL(INEXT3) do {                                                     \
    s0 = s1; s1 = s2;                                                         \
    const int in3_ = (INEXT3) < nu ? (INEXT3) : (nu - 1);                     \
    s2 = src_of(ti0 + in3_ * 512);                                            \
    t_cur += 512;                                                             \
  } while (0)

#define UNIT_EVEN(WA, WB, I) do {                                             \
    TAPS();                                                                   \
    STAGE(ybB + s1 + 4 * lane, b3);                                           \
    WCOMP(WA, b0, oA);                                                        \
    STAGE(ybA + s2 + 4 * lane, b0);                                           \
    WCOMP(WB, b1, oA + out_bs);                                               \
    ROLL((I) + 3);                                                            \
  } while (0)

#define UNIT_ODD(WA, WB, I) do {                                              \
    TAPS();                                                                   \
    STAGE(ybB + s1 + 4 * lane, b1);                                           \
    WCOMP(WA, b2, oA);                                                        \
    STAGE(ybA + s2 + 4 * lane, b2);                                           \
    WCOMP(WB, b3, oA + out_bs);                                               \
    ROLL((I) + 3);                                                            \
  } while (0)

    // ---- prologue: windows 0,1,2 ----
    STAGE(ybA + s0 + 4 * lane, b0);
    STAGE(ybB + s0 + 4 * lane, b1);
    STAGE(ybA + s1 + 4 * lane, b2);

    // ---- unit 0 (even), waits 3,4; tile-0 clamp fallback ----
    TAPS();
    STAGE(ybB + s1 + 4 * lane, b3);
    if (t_cur != 0) {
        WCOMP(3, b0, oA);
    } else {
        asm volatile("s_waitcnt vmcnt(3)" ::: "memory");
        __builtin_amdgcn_sched_barrier(0);
        const int y0a_ = ra + s0, y0b_ = rb + s0;
        vf2 o_;
        o_.x = herm(ybA[y0a_ > 0 ? y0a_ - 1 : 0], ybA[y0a_],
                    ybA[y0a_ + 1], ybA[y0a_ + 2], xa);
        o_.y = herm(ybA[y0b_ > 0 ? y0b_ - 1 : 0], ybA[y0b_],
                    ybA[y0b_ + 1], ybA[y0b_ + 2], xb);
        __builtin_nontemporal_store(o_, (vf2*)oA);
    }
    STAGE(ybA + s2 + 4 * lane, b0);
    if (t_cur != 0) {
        WCOMP(4, b1, oA + out_bs);
    } else {
        asm volatile("s_waitcnt vmcnt(4)" ::: "memory");
        __builtin_amdgcn_sched_barrier(0);
        const int y0a_ = ra + s0, y0b_ = rb + s0;
        vf2 o_;
        o_.x = herm(ybB[y0a_ > 0 ? y0a_ - 1 : 0], ybB[y0a_],
                    ybB[y0a_ + 1], ybB[y0a_ + 2], xa);
        o_.y = herm(ybB[y0b_ > 0 ? y0b_ - 1 : 0], ybB[y0b_],
                    ybB[y0b_ + 1], ybB[y0b_ + 2], xb);
        __builtin_nontemporal_store(o_, (vf2*)(oA + out_bs));
    }
    ROLL(3);

    // ---- unit 1 (odd), waits 5,6 ----
    UNIT_ODD(5, 6, 1);

    // ---- steady units, waits 6,6 ----
    int i = 2;
    for (; i + 1 < nu; i += 2) {
        UNIT_EVEN(6, 6, i);
        UNIT_ODD(6, 6, i + 1);
    }
    if (i < nu) UNIT_EVEN(6, 6, i);

    asm volatile("s_waitcnt vmcnt(0)" ::: "memory");

    // ---- tail samples (out_bs - ntile*128 per channel), spare waves ----
    const int ntail_waves = (tailn * NCH + 63) >> 6;   // 26 for tailn=52
    if (gid >= NWAVES - ntail_waves) {
        const int tix = (gid - (NWAVES - ntail_waves)) * 64 + lane;
        if (tix < tailn * NCH) {
            const int ch = tix / tailn;
            const int jr = tix - ch * tailn;
            const int j  = (ntile << 7) + jr;
            const uint64_t p = (uint64_t)(uint32_t)j * S43;
            const int y0 = (int)(p >> FRACSH);
            float xx = (float)((uint32_t)(p >> (FRACSH - 24)) & 0xFFFFFFu)
                       * 0x1p-24f;
            if (j == out_bs - 1) xx = rintf(xx);   // np: x[-1] = round(x[-1])
            const float* yc = y + (size_t)ch * (size_t)in_bs;
            const int im1 = y0 > 0 ? y0 - 1 : 0;
            const int i1  = min(y0 + 1, in_bs - 1);
            const int i2  = min(y0 + 2, in_bs - 1);
            out[(size_t)ch * (size_t)out_bs + j] =
                herm(yc[im1], yc[y0], yc[i1], yc[i2], xx);
        }
    }

#undef STAGE
#undef TAPS
#undef WCOMP
#undef ROLL
#undef UNIT_EVEN
#undef UNIT_ODD
}

extern "C" void kernel_launch(void* const* d_in, const int* in_sizes, int n_in,
                              void* d_out, int out_size, void* d_ws, size_t ws_size,
                              hipStream_t stream)
{
    const float* y   = (const float*)d_in[0];
    float*       out = (float*)d_out;

    const int out_bs = in_sizes[1];           // 963380
    const int n_ch   = out_size / out_bs;     // 32
    const int in_bs  = in_sizes[0] / n_ch;    // 1048576

    // identical IEEE fp64 value to numpy's (in_bs-1)/(out_bs-1) + 1e-12,
    // then exact 43-bit fixed point (error <= 2^-44 per step, ~5.5e-8 total)
    const double scaling = (double)(in_bs - 1) / (double)(out_bs - 1) + 1e-12;
    const unsigned long long S43 =
        (unsigned long long)(scaling * 8796093022208.0 + 0.5);   // 2^43

    const int ntile = out_bs / TILE;          // 7526
    const int tailn = out_bs - ntile * TILE;  // 52

    hermite_pers_kernel<<<dim3(NBLOCKS), 128, 0, stream>>>(
        y, out, out_bs, in_bs, S43, ntile, tailn);
}